// Round 12
// baseline (41.390 us; speedup 1.0000x reference)
//
#include <hip/hip_runtime.h>
#include <hip/hip_bf16.h>
#include <math.h>

#define B_N 8192
#define U_N 256
#define F_N 128
#define UG  32    // u's per block = 2 MFMA n-tiles
#define BT  128   // b-rows per block = 8 waves x 16
#define NREP 8    // DIAGNOSTIC: x8 idempotent repeat to surface rocprof counters

typedef __attribute__((ext_vector_type(8))) short short8;   // 8 bf16
typedef __attribute__((ext_vector_type(4))) float f32x4;    // MFMA C/D

static __device__ __forceinline__ unsigned short f2bf(float v) {
  __hip_bfloat16 h = __float2bfloat16(v);
  return *reinterpret_cast<unsigned short*>(&h);
}

// Physical byte offsets with XOR swizzle (write and read use the same map).
static __device__ __forceinline__ int wf_off(int tile, int kk, int lane) {
  return tile * 8192 + kk * 1024 + ((lane * 16) ^ ((kk & 3) << 5));
}
static __device__ __forceinline__ int bf_off(int tl, int kk, int lane) {
  return tl * 4096 + kk * 1024 + ((lane * 16) ^ (kk << 5));
}

// DIAGNOSTIC BUILD: byte-identical R10 dataflow, whole body repeated NREP
// times (idempotent; pointers laundered so loads re-issue). Single dispatch
// ~8x longer -> rises into rocprof top-5 so we finally see FETCH_SIZE /
// VALUBusy / MfmaUtil / Occupancy for OUR kernel instead of harness fills.
__global__ __launch_bounds__(512, 4) void bp_kernel(
    const float* __restrict__ x, const float* __restrict__ shift,
    const float* __restrict__ semi, const float* __restrict__ sharp,
    const float* __restrict__ mult, float* __restrict__ out) {
  __shared__ __align__(16) short Wf[2 * 8 * 64 * 8];    // 16 KB
  __shared__ __align__(16) short Bfx[8 * 4 * 64 * 8];   // 32 KB
  __shared__ __align__(16) float Cs[UG];

  const int tid  = threadIdx.x;
  const int l    = tid & 63;
  const int w    = tid >> 6;
  const int u0   = blockIdx.y * UG;
  const int bbase = blockIdx.x * BT;

#pragma nounroll
  for (int rep = 0; rep < NREP; ++rep) {
    const float* xp  = x;
    const float* shp = shift;
    const float* sep = semi;
    asm volatile("" : "+r"(xp), "+r"(shp), "+r"(sep));  // defeat cross-rep CSE

    // ---- 1) x loads: wave-local rows, lane-contiguous float4 ----
    const int xr_half = l >> 5;
    const int xf      = (l & 31) * 4;
    float4 xl[8];
#pragma unroll
    for (int p = 0; p < 8; ++p) {
      const int row = bbase + w * 16 + p * 2 + xr_half;
      xl[p] = *reinterpret_cast<const float4*>(xp + (size_t)row * F_N + xf);
    }

    // ---- 2) prep loads + compute: W fragments (swizzled) + Cs ----
    {
      const int pu  = tid >> 5;
      const int pf  = (tid & 31) * 4;
      const int kkq = pf >> 5;
      const int lnq16 = ((pf >> 3) & 3) * 16;
      const int j0q = pf & 7;
      char* wfb = reinterpret_cast<char*>(Wf);
#pragma unroll
      for (int q = 0; q < 2; ++q) {
        const float4 sf = *reinterpret_cast<const float4*>(shp + (size_t)(u0 + pu + q * 16) * F_N + pf);
        const float4 se = *reinterpret_cast<const float4*>(sep + (size_t)(u0 + pu + q * 16) * F_N + pf);
        const float ssv[4] = {sf.x, sf.y, sf.z, sf.w};
        const float aav[4] = {se.x, se.y, se.z, se.w};
        unsigned short qi[4], qb[4];
        float csum = 0.f;
#pragma unroll
        for (int j = 0; j < 4; ++j) {
          float inv = __builtin_amdgcn_rcpf(aav[j] * aav[j]);
          qi[j] = f2bf(inv);
          qb[j] = f2bf(2.0f * ssv[j] * inv);
          csum += ssv[j] * ssv[j] * inv;
        }
        const int u_loc = pu + q * 16;
        const int lnq   = lnq16 + (u_loc & 15);
        *reinterpret_cast<uint2*>(wfb + wf_off(q, kkq,     lnq) + j0q * 2) = *reinterpret_cast<uint2*>(qi);
        *reinterpret_cast<uint2*>(wfb + wf_off(q, kkq + 4, lnq) + j0q * 2) = *reinterpret_cast<uint2*>(qb);
        csum += __shfl_xor(csum, 1, 64);
        csum += __shfl_xor(csum, 2, 64);
        csum += __shfl_xor(csum, 4, 64);
        csum += __shfl_xor(csum, 8, 64);
        csum += __shfl_xor(csum, 16, 64);
        if ((tid & 31) == 0) Cs[u_loc] = csum;
      }
    }

    // ---- 3) x -> bf16 fragments into Bfx (wave-local tile, swizzled) ----
    {
      const int bkk = (l & 31) >> 3;
      const int blg = ((l & 31) >> 1) & 3;
      const int bj0 = (l & 1) * 4;
#pragma unroll
      for (int p = 0; p < 8; ++p) {
        const int rt   = p * 2 + xr_half;
        const int lane = blg * 16 + rt;
        unsigned short q4[4] = {f2bf(xl[p].x), f2bf(xl[p].y), f2bf(xl[p].z), f2bf(xl[p].w)};
        *reinterpret_cast<uint2*>(reinterpret_cast<char*>(Bfx) + bf_off(w, bkk, lane) + bj0 * 2) =
            *reinterpret_cast<uint2*>(q4);
      }
    }

    __syncthreads();

    // ---- 4) fragments from LDS; x^2 frags computed in-register ----
    short8 bx[4], bx2[4];
#pragma unroll
    for (int k4 = 0; k4 < 4; ++k4)
      bx[k4] = *reinterpret_cast<const short8*>(
          reinterpret_cast<const char*>(Bfx) + bf_off(w, k4, l));
#pragma unroll
    for (int k4 = 0; k4 < 4; ++k4) {
      short8 o;
#pragma unroll
      for (int j = 0; j < 8; ++j) {
        const float f = __uint_as_float(((unsigned)(unsigned short)bx[k4][j]) << 16);
        o[j] = (short)f2bf(f * f);
      }
      bx2[k4] = o;
    }

    // ---- 5) GEMM: K=256, 16 MFMAs ----
    f32x4 acc0 = {0.f, 0.f, 0.f, 0.f};
    f32x4 acc1 = {0.f, 0.f, 0.f, 0.f};
    const char* wfb = reinterpret_cast<const char*>(Wf);
#pragma unroll
    for (int kk = 0; kk < 8; ++kk) {
      const short8 b  = (kk < 4) ? bx2[kk] : bx[kk - 4];
      const short8 a0 = *reinterpret_cast<const short8*>(wfb + wf_off(0, kk, l));
      const short8 a1 = *reinterpret_cast<const short8*>(wfb + wf_off(1, kk, l));
      acc0 = __builtin_amdgcn_mfma_f32_16x16x32_bf16(a0, b, acc0, 0, 0, 0);
      acc1 = __builtin_amdgcn_mfma_f32_16x16x32_bf16(a1, b, acc1, 0, 0, 0);
    }

    // ---- 6) epilogue ----
    const int lg = l >> 4;
    const int ln = l & 15;
    const int brow = bbase + w * 16 + ln;
#pragma unroll
    for (int t = 0; t < 2; ++t) {
      const f32x4 acc = t ? acc1 : acc0;
      const int ub = t * 16 + lg * 4;
      const float4 c4  = *reinterpret_cast<const float4*>(&Cs[ub]);
      const float4 sh4 = *reinterpret_cast<const float4*>(&sharp[u0 + ub]);
      const float4 mu4 = *reinterpret_cast<const float4*>(&mult[u0 + ub]);
      const float cc[4]  = {c4.x, c4.y, c4.z, c4.w};
      const float shs[4] = {sh4.x, sh4.y, sh4.z, sh4.w};
      const float mus[4] = {mu4.x, mu4.y, mu4.z, mu4.w};
      float res[4];
#pragma unroll
      for (int r = 0; r < 4; ++r) {
        const float quad = acc[r] + cc[r];
        const float e = __expf(shs[r] * (quad - 1.0f));
        res[r] = mus[r] * __builtin_amdgcn_rcpf(1.0f + e);
      }
      *reinterpret_cast<float4*>(&out[(size_t)brow * U_N + u0 + ub]) =
          make_float4(res[0], res[1], res[2], res[3]);
    }

    __syncthreads();   // protect Bfx/Wf rewrite in next rep
  }
}

extern "C" void kernel_launch(void* const* d_in, const int* in_sizes, int n_in,
                              void* d_out, int out_size, void* d_ws, size_t ws_size,
                              hipStream_t stream) {
  (void)in_sizes; (void)n_in; (void)out_size; (void)d_ws; (void)ws_size;
  const float* x     = (const float*)d_in[0];
  const float* shift = (const float*)d_in[1];
  const float* semi  = (const float*)d_in[2];
  const float* sharp = (const float*)d_in[3];
  const float* mult  = (const float*)d_in[4];
  float* out = (float*)d_out;

  bp_kernel<<<dim3(B_N / BT, U_N / UG), 512, 0, stream>>>(x, shift, semi, sharp, mult, out);
}

// Round 13
// 13.573 us; speedup vs baseline: 3.0494x; 3.0494x over previous
//
#include <hip/hip_runtime.h>
#include <hip/hip_bf16.h>
#include <math.h>

#define B_N 8192
#define U_N 256
#define F_N 128
#define UG  32    // u's per block = 2 MFMA n-tiles
#define BT  128   // b-rows per block = 8 waves x 16

typedef __attribute__((ext_vector_type(8))) short short8;   // 8 bf16
typedef __attribute__((ext_vector_type(4))) float f32x4;    // MFMA C/D

static __device__ __forceinline__ unsigned short f2bf(float v) {
  __hip_bfloat16 h = __float2bfloat16(v);   // pairs fold to v_cvt_pk_bf16_f32
  return *reinterpret_cast<unsigned short*>(&h);
}

// Wf byte offset. Swizzle makes BOTH the lnq16 write-dimension (lane bits 4-5)
// and kk bank-visible: write = 2 lanes / 8B half-slot (2-way, free per m136);
// read  = per-8-lane phase a permutation of the 8 slots (conflict-free).
// Bijective per (tile,kk): bits 4-5 of lane*16 are XORed by a function of
// untouched higher bits. Same map used by writer and reader.
static __device__ __forceinline__ int wf_off(int tile, int kk, int lane) {
  return tile * 8192 + kk * 1024 +
         ((lane * 16) ^ ((kk & 3) << 5) ^ (((lane >> 4) & 3) << 4));
}

// R10 structure minus Bfx: 512 thr, 32 u x 128 b, one barrier.
// x loads go DIRECTLY into B-fragment registers (16 lines/instr, same as the
// staged path) -- no x LDS, no conflicted fragment writes.
__global__ __launch_bounds__(512, 4) void bp_kernel(
    const float* __restrict__ x, const float* __restrict__ shift,
    const float* __restrict__ semi, const float* __restrict__ sharp,
    const float* __restrict__ mult, float* __restrict__ out) {
  __shared__ __align__(16) short Wf[2 * 8 * 64 * 8];    // 16 KB
  __shared__ __align__(16) float Cs[UG];

  const int tid  = threadIdx.x;
  const int l    = tid & 63;
  const int w    = tid >> 6;          // wave 0..7 -> b-rows w*16..+15
  const int lg   = l >> 4;            // 0..3 (k-group)
  const int ln   = l & 15;            // 0..15 (b-row / u-row)
  const int u0   = blockIdx.y * UG;
  const int brow0 = blockIdx.x * BT + w * 16;

  // ---- 1) x loads, fragment order: row=ln, cols lg*8 + s4*32 (+4) ----
  const float* xrow = x + (size_t)(brow0 + ln) * F_N;
  float4 xa[4], xb[4];
#pragma unroll
  for (int s4 = 0; s4 < 4; ++s4) {
    xa[s4] = *reinterpret_cast<const float4*>(xrow + s4 * 32 + lg * 8);
    xb[s4] = *reinterpret_cast<const float4*>(xrow + s4 * 32 + lg * 8 + 4);
  }

  // ---- 2) prep: lane-contiguous loads; W fragments (2-way-clean swizzle) ----
  {
    const int pu  = tid >> 5;            // 0..15
    const int pf  = (tid & 31) * 4;      // 0..124
    const int kkq = pf >> 5;             // 0..3
    const int lnq = ((pf >> 3) & 3) * 16 + pu;   // fragment lane
    const int j0q = pf & 7;              // 0 or 4
    char* wfb = reinterpret_cast<char*>(Wf);
#pragma unroll
    for (int q = 0; q < 2; ++q) {
      const int u_loc = pu + q * 16;     // 0..31 ; tile = q
      const float4 sf = *reinterpret_cast<const float4*>(shift + (size_t)(u0 + u_loc) * F_N + pf);
      const float4 se = *reinterpret_cast<const float4*>(semi  + (size_t)(u0 + u_loc) * F_N + pf);
      const float ssv[4] = {sf.x, sf.y, sf.z, sf.w};
      const float aav[4] = {se.x, se.y, se.z, se.w};
      unsigned short qi[4], qb[4];
      float csum = 0.f;
#pragma unroll
      for (int j = 0; j < 4; ++j) {
        float inv = __builtin_amdgcn_rcpf(aav[j] * aav[j]);
        qi[j] = f2bf(inv);
        qb[j] = f2bf(2.0f * ssv[j] * inv);
        csum += ssv[j] * ssv[j] * inv;
      }
      *reinterpret_cast<uint2*>(wfb + wf_off(q, kkq,     lnq) + j0q * 2) = *reinterpret_cast<uint2*>(qi);
      *reinterpret_cast<uint2*>(wfb + wf_off(q, kkq + 4, lnq) + j0q * 2) = *reinterpret_cast<uint2*>(qb);
      csum += __shfl_xor(csum, 1, 64);
      csum += __shfl_xor(csum, 2, 64);
      csum += __shfl_xor(csum, 4, 64);
      csum += __shfl_xor(csum, 8, 64);
      csum += __shfl_xor(csum, 16, 64);
      if ((tid & 31) == 0) Cs[u_loc] = csum;
    }
  }

  // ---- 3) pack B-fragments in registers: kk<4 -> x^2 ; kk>=4 -> x ----
  short8 fx[8];
#pragma unroll
  for (int s4 = 0; s4 < 4; ++s4) {
    const float xs[8] = {xa[s4].x, xa[s4].y, xa[s4].z, xa[s4].w,
                         xb[s4].x, xb[s4].y, xb[s4].z, xb[s4].w};
    short8 a2, a1;
#pragma unroll
    for (int j = 0; j < 8; ++j) {
      a2[j] = (short)f2bf(xs[j] * xs[j]);
      a1[j] = (short)f2bf(xs[j]);
    }
    fx[s4] = a2; fx[s4 + 4] = a1;
  }

  __syncthreads();

  // ---- 4) GEMM: K=256, 16 MFMAs; W as A-operand -> D[row=u][col=b] ----
  f32x4 acc0 = {0.f, 0.f, 0.f, 0.f};
  f32x4 acc1 = {0.f, 0.f, 0.f, 0.f};
  const char* wfb = reinterpret_cast<const char*>(Wf);
#pragma unroll
  for (int kk = 0; kk < 8; ++kk) {
    const short8 b  = fx[kk];
    const short8 a0 = *reinterpret_cast<const short8*>(wfb + wf_off(0, kk, l));
    const short8 a1 = *reinterpret_cast<const short8*>(wfb + wf_off(1, kk, l));
    acc0 = __builtin_amdgcn_mfma_f32_16x16x32_bf16(a0, b, acc0, 0, 0, 0);
    acc1 = __builtin_amdgcn_mfma_f32_16x16x32_bf16(a1, b, acc1, 0, 0, 0);
  }

  // ---- 5) epilogue: thread owns b = brow0+ln, u = u0+t*16+lg*4+r ----
  const int brow = brow0 + ln;
#pragma unroll
  for (int t = 0; t < 2; ++t) {
    const f32x4 acc = t ? acc1 : acc0;
    const int ub = t * 16 + lg * 4;
    const float4 c4  = *reinterpret_cast<const float4*>(&Cs[ub]);
    const float4 sh4 = *reinterpret_cast<const float4*>(&sharp[u0 + ub]);
    const float4 mu4 = *reinterpret_cast<const float4*>(&mult[u0 + ub]);
    const float cc[4]  = {c4.x, c4.y, c4.z, c4.w};
    const float shs[4] = {sh4.x, sh4.y, sh4.z, sh4.w};
    const float mus[4] = {mu4.x, mu4.y, mu4.z, mu4.w};
    float res[4];
#pragma unroll
    for (int r = 0; r < 4; ++r) {
      const float quad = acc[r] + cc[r];
      const float e = __expf(shs[r] * (quad - 1.0f));     // = exp(-z); inf when saturated
      res[r] = mus[r] * __builtin_amdgcn_rcpf(1.0f + e);  // rcp(inf)=+0 -> +-0
    }
    *reinterpret_cast<float4*>(&out[(size_t)brow * U_N + u0 + ub]) =
        make_float4(res[0], res[1], res[2], res[3]);
  }
}

extern "C" void kernel_launch(void* const* d_in, const int* in_sizes, int n_in,
                              void* d_out, int out_size, void* d_ws, size_t ws_size,
                              hipStream_t stream) {
  (void)in_sizes; (void)n_in; (void)out_size; (void)d_ws; (void)ws_size;
  const float* x     = (const float*)d_in[0];
  const float* shift = (const float*)d_in[1];
  const float* semi  = (const float*)d_in[2];
  const float* sharp = (const float*)d_in[3];
  const float* mult  = (const float*)d_in[4];
  float* out = (float*)d_out;

  bp_kernel<<<dim3(B_N / BT, U_N / UG), 512, 0, stream>>>(x, shift, semi, sharp, mult, out);
}

// Round 14
// 11.919 us; speedup vs baseline: 3.4726x; 1.1388x over previous
//
#include <hip/hip_runtime.h>
#include <hip/hip_bf16.h>
#include <math.h>

#define B_N 8192
#define U_N 256
#define F_N 128
#define UG  32    // u's per block = 2 MFMA n-tiles
#define BT  128   // b-rows per block = 8 waves x 16

typedef __attribute__((ext_vector_type(8))) short short8;   // 8 bf16
typedef __attribute__((ext_vector_type(4))) float f32x4;    // MFMA C/D

static __device__ __forceinline__ unsigned short f2bf(float v) {
  __hip_bfloat16 h = __float2bfloat16(v);
  return *reinterpret_cast<unsigned short*>(&h);
}

// Byte-offset maps, used identically on write and read sides.
// Extra term ^(((lane>>4)&3)<<4) pulls the formerly bank-invisible lane
// bits 4-5 (byte bits 8-9) into bank bits 4-5: write phases (16 lanes x 8B)
// go 4-way -> <=2-way (free, m136); read phases stay minimal permutations.
static __device__ __forceinline__ int wf_off(int tile, int kk, int lane) {
  return tile * 8192 + kk * 1024 +
         ((lane * 16) ^ ((kk & 3) << 5) ^ (((lane >> 4) & 3) << 4));
}
static __device__ __forceinline__ int bf_off(int tl, int kk, int lane) {
  return tl * 4096 + kk * 1024 +
         ((lane * 16) ^ (kk << 5) ^ (((lane >> 4) & 3) << 4));
}

// R10 structure (512 thr, 32 u x 128 b, one barrier), conflict-free LDS maps.
__global__ __launch_bounds__(512, 4) void bp_kernel(
    const float* __restrict__ x, const float* __restrict__ shift,
    const float* __restrict__ semi, const float* __restrict__ sharp,
    const float* __restrict__ mult, float* __restrict__ out) {
  __shared__ __align__(16) short Wf[2 * 8 * 64 * 8];    // 16 KB
  __shared__ __align__(16) short Bfx[8 * 4 * 64 * 8];   // 32 KB
  __shared__ __align__(16) float Cs[UG];

  const int tid  = threadIdx.x;
  const int l    = tid & 63;
  const int w    = tid >> 6;          // wave 0..7 -> owns b-rows w*16..+15
  const int u0   = blockIdx.y * UG;
  const int bbase = blockIdx.x * BT;

  // ---- 1) x loads: wave-local rows, lane-contiguous float4 ----
  const int xr_half = l >> 5;         // 0/1
  const int xf      = (l & 31) * 4;   // f-quad base 0..124
  float4 xl[8];
#pragma unroll
  for (int p = 0; p < 8; ++p) {
    const int row = bbase + w * 16 + p * 2 + xr_half;
    xl[p] = *reinterpret_cast<const float4*>(x + (size_t)row * F_N + xf);
  }

  // ---- 2) prep loads + compute: W fragments (swizzled) + Cs ----
  {
    const int pu  = tid >> 5;            // 0..15
    const int pf  = (tid & 31) * 4;      // 0..124
    const int kkq = pf >> 5;             // 0..3
    const int lnq16 = ((pf >> 3) & 3) * 16;
    const int j0q = pf & 7;              // 0 or 4
    char* wfb = reinterpret_cast<char*>(Wf);
#pragma unroll
    for (int q = 0; q < 2; ++q) {
      const int u_loc = pu + q * 16;     // 0..31 ; tile = q
      const float4 sf = *reinterpret_cast<const float4*>(shift + (size_t)(u0 + u_loc) * F_N + pf);
      const float4 se = *reinterpret_cast<const float4*>(semi  + (size_t)(u0 + u_loc) * F_N + pf);
      const float ssv[4] = {sf.x, sf.y, sf.z, sf.w};
      const float aav[4] = {se.x, se.y, se.z, se.w};
      unsigned short qi[4], qb[4];
      float csum = 0.f;
#pragma unroll
      for (int j = 0; j < 4; ++j) {
        float inv = __builtin_amdgcn_rcpf(aav[j] * aav[j]);
        qi[j] = f2bf(inv);
        qb[j] = f2bf(2.0f * ssv[j] * inv);
        csum += ssv[j] * ssv[j] * inv;
      }
      const int lnq = lnq16 + (u_loc & 15);
      *reinterpret_cast<uint2*>(wfb + wf_off(q, kkq,     lnq) + j0q * 2) = *reinterpret_cast<uint2*>(qi);
      *reinterpret_cast<uint2*>(wfb + wf_off(q, kkq + 4, lnq) + j0q * 2) = *reinterpret_cast<uint2*>(qb);
      csum += __shfl_xor(csum, 1, 64);
      csum += __shfl_xor(csum, 2, 64);
      csum += __shfl_xor(csum, 4, 64);
      csum += __shfl_xor(csum, 8, 64);
      csum += __shfl_xor(csum, 16, 64);
      if ((tid & 31) == 0) Cs[u_loc] = csum;
    }
  }

  // ---- 3) x -> bf16 fragments into Bfx (wave-local tile, swizzled) ----
  {
    const int bkk = (l & 31) >> 3;        // kk 0..3
    const int blg = ((l & 31) >> 1) & 3;  // k-group within fragment
    const int bj0 = (l & 1) * 4;          // j half
#pragma unroll
    for (int p = 0; p < 8; ++p) {
      const int rt   = p * 2 + xr_half;
      const int lane = blg * 16 + rt;
      unsigned short q4[4] = {f2bf(xl[p].x), f2bf(xl[p].y), f2bf(xl[p].z), f2bf(xl[p].w)};
      *reinterpret_cast<uint2*>(reinterpret_cast<char*>(Bfx) + bf_off(w, bkk, lane) + bj0 * 2) =
          *reinterpret_cast<uint2*>(q4);
    }
  }

  __syncthreads();

  // ---- 4) fragments from LDS; x^2 frags computed in-register ----
  short8 bx[4], bx2[4];
#pragma unroll
  for (int k4 = 0; k4 < 4; ++k4)
    bx[k4] = *reinterpret_cast<const short8*>(
        reinterpret_cast<const char*>(Bfx) + bf_off(w, k4, l));
#pragma unroll
  for (int k4 = 0; k4 < 4; ++k4) {
    short8 o;
#pragma unroll
    for (int j = 0; j < 8; ++j) {
      const float f = __uint_as_float(((unsigned)(unsigned short)bx[k4][j]) << 16);
      o[j] = (short)f2bf(f * f);
    }
    bx2[k4] = o;
  }

  // ---- 5) GEMM: K=256, 16 MFMAs; W as A-operand -> D[row=u][col=b] ----
  f32x4 acc0 = {0.f, 0.f, 0.f, 0.f};
  f32x4 acc1 = {0.f, 0.f, 0.f, 0.f};
  const char* wfb = reinterpret_cast<const char*>(Wf);
#pragma unroll
  for (int kk = 0; kk < 8; ++kk) {
    const short8 b  = (kk < 4) ? bx2[kk] : bx[kk - 4];
    const short8 a0 = *reinterpret_cast<const short8*>(wfb + wf_off(0, kk, l));
    const short8 a1 = *reinterpret_cast<const short8*>(wfb + wf_off(1, kk, l));
    acc0 = __builtin_amdgcn_mfma_f32_16x16x32_bf16(a0, b, acc0, 0, 0, 0);
    acc1 = __builtin_amdgcn_mfma_f32_16x16x32_bf16(a1, b, acc1, 0, 0, 0);
  }

  // ---- 6) epilogue: thread owns b = bbase + w*16 + ln, u = u0+t*16+lg*4+r ----
  const int lg = l >> 4;
  const int ln = l & 15;
  const int brow = bbase + w * 16 + ln;
#pragma unroll
  for (int t = 0; t < 2; ++t) {
    const f32x4 acc = t ? acc1 : acc0;
    const int ub = t * 16 + lg * 4;
    const float4 c4  = *reinterpret_cast<const float4*>(&Cs[ub]);
    const float4 sh4 = *reinterpret_cast<const float4*>(&sharp[u0 + ub]);
    const float4 mu4 = *reinterpret_cast<const float4*>(&mult[u0 + ub]);
    const float cc[4]  = {c4.x, c4.y, c4.z, c4.w};
    const float shs[4] = {sh4.x, sh4.y, sh4.z, sh4.w};
    const float mus[4] = {mu4.x, mu4.y, mu4.z, mu4.w};
    float res[4];
#pragma unroll
    for (int r = 0; r < 4; ++r) {
      const float quad = acc[r] + cc[r];
      const float e = __expf(shs[r] * (quad - 1.0f));     // = exp(-z); inf when saturated
      res[r] = mus[r] * __builtin_amdgcn_rcpf(1.0f + e);  // rcp(inf)=+0 -> +-0
    }
    *reinterpret_cast<float4*>(&out[(size_t)brow * U_N + u0 + ub]) =
        make_float4(res[0], res[1], res[2], res[3]);
  }
}

extern "C" void kernel_launch(void* const* d_in, const int* in_sizes, int n_in,
                              void* d_out, int out_size, void* d_ws, size_t ws_size,
                              hipStream_t stream) {
  (void)in_sizes; (void)n_in; (void)out_size; (void)d_ws; (void)ws_size;
  const float* x     = (const float*)d_in[0];
  const float* shift = (const float*)d_in[1];
  const float* semi  = (const float*)d_in[2];
  const float* sharp = (const float*)d_in[3];
  const float* mult  = (const float*)d_in[4];
  float* out = (float*)d_out;

  bp_kernel<<<dim3(B_N / BT, U_N / UG), 512, 0, stream>>>(x, shift, semi, sharp, mult, out);
}